// Round 3
// baseline (494.860 us; speedup 1.0000x reference)
//
#include <hip/hip_runtime.h>
#include <hip/hip_bf16.h>

// y[b,f,c] = sum_hw x[b,c,hw] * k[f,c,hw];  out[b, f*C + c]
// B=256, F=16, C=256, HW=1024, fp32.
//
// R4 lesson: no waves-per-eu hint (caps allocator -> loop spills).
// R7: stage ALL of K[.,c,.] (64 KB LDS) once; barrier-free main loop.
// R8: BT=64/512thr + XCD swizzle -> NEUTRAL.  R9: RB=4 (LDS 4:1) -> NEUTRAL.
//     Kernel pinned at ~64-70us (dur - 2x ~160us poison fills) across three
//     structurally different configs => limiter is an invariant: every
//     version read each 4KB x-row as 16 temporally-scattered 256B touches
//     (~4000 cyc apart) => ~16 DRAM row activations per 4KB row.
// R10 (this round): consume each x-row in ONE burst. grid=256 (1 block/c,
//     exactly 1 block/CU, K staged once = 16.7MB min). 8 waves x 32 b;
//     per super-iter a wave issues 16 back-to-back dwordx4 covering 4
//     whole 4KB rows (1KB/instr, s-major so compute starts at vmcnt(12)).
//     hw spans lanes -> 64-lane butterfly epilogue, one dword store per
//     lane per super-iter; no LDS write-back, no barriers after staging.
//     Per-CU per super-iter: HBM 12800 cyc, LDS ~6000, VALU ~7600 -> HBM-
//     bound. Predict kernel 64 -> ~48us. If neutral again: ROOFLINE.

constexpr int Bb = 256;
constexpr int Ff = 16;
constexpr int Cc = 256;
constexpr int HW = 1024;
constexpr int CHW = Cc * HW;

constexpr int NTHREADS = 512;
constexpr int WAVES = 8;
constexpr int BPW = Bb / WAVES;     // 32 b per wave
constexpr int RB = 4;               // b (rows) per super-iter
constexpr int NSI = BPW / RB;       // 8 super-iters

__device__ __forceinline__ float dot4(float4 a, float4 b) {
    return a.x * b.x + a.y * b.y + a.z * b.z + a.w * b.w;
}
__device__ __forceinline__ float4 sel4(bool c, float4 a, float4 b) {
    return c ? a : b;               // 4x v_cndmask
}

__global__ __launch_bounds__(NTHREADS)   // no waves-per-eu hint (R4 lesson)
void sle_kernel(const float* __restrict__ x, const float* __restrict__ k,
                float* __restrict__ out) {
    __shared__ float ldsK[Ff * HW];           // 64 KiB: whole K for this c

    const int t    = threadIdx.x;
    const int lane = t & 63;
    const int w    = t >> 6;                  // wave 0..7

    // XCD-aware c decode: same-XCD blocks (g%8 equal) own 32 consecutive c
    const int g = blockIdx.x;
    const int c = (g & 7) * 32 + (g >> 3);    // bijective over 0..255

    // ---- stage K[f][0..HW) for this c: 16384 floats, 8 float4/thread ----
    {
        const int fr = t >> 5, lane32 = t & 31;   // 32 threads per f-row
        const float4* src = (const float4*)(k + (size_t)fr * CHW + (size_t)c * HW);
        float4* dst = (float4*)(ldsK + fr * HW);
#pragma unroll
        for (int q = 0; q < 8; ++q)
            dst[lane32 + 32 * q] = src[lane32 + 32 * q];
    }
    __syncthreads();                          // only barrier in the kernel

    const float* xc   = x + (size_t)c * HW + 4 * lane;
    float*       outc = out + c;

    for (int si = 0; si < NSI; ++si) {
        const int b0 = w * BPW + si * RB;

        // ---- 16 back-to-back 1KB loads: 4 complete 4KB rows ----
        // s-major issue order: compute for s=0 needs only the first 4.
        float4 xv[RB][4];
#pragma unroll
        for (int s = 0; s < 4; ++s)
#pragma unroll
            for (int bb = 0; bb < RB; ++bb)
                xv[bb][s] = *(const float4*)(xc + (size_t)(b0 + bb) * CHW + s * 256);

        float4 a4[RB][4];
#pragma unroll
        for (int bb = 0; bb < RB; ++bb)
#pragma unroll
            for (int gg = 0; gg < 4; ++gg)
                a4[bb][gg] = make_float4(0.f, 0.f, 0.f, 0.f);

        // ---- compute: per s, 16 ds_read_b128 + 64 dot4 ----
#pragma unroll
        for (int s = 0; s < 4; ++s) {
            const float* kp = ldsK + s * 256 + 4 * lane;
#pragma unroll
            for (int gg = 0; gg < 4; ++gg) {
                const float4 k0 = *(const float4*)(kp + (4 * gg + 0) * HW);
                const float4 k1 = *(const float4*)(kp + (4 * gg + 1) * HW);
                const float4 k2 = *(const float4*)(kp + (4 * gg + 2) * HW);
                const float4 k3 = *(const float4*)(kp + (4 * gg + 3) * HW);
#pragma unroll
                for (int bb = 0; bb < RB; ++bb) {
                    a4[bb][gg].x += dot4(xv[bb][s], k0);
                    a4[bb][gg].y += dot4(xv[bb][s], k1);
                    a4[bb][gg].z += dot4(xv[bb][s], k2);
                    a4[bb][gg].w += dot4(xv[bb][s], k3);
                }
            }
        }

        // ---- butterfly-reduce each of the 16 float4 across 64 lanes ----
#pragma unroll
        for (int bb = 0; bb < RB; ++bb)
#pragma unroll
            for (int gg = 0; gg < 4; ++gg) {
                float4 v = a4[bb][gg];
#pragma unroll
                for (int m = 1; m <= 32; m <<= 1) {
                    v.x += __shfl_xor(v.x, m);
                    v.y += __shfl_xor(v.y, m);
                    v.z += __shfl_xor(v.z, m);
                    v.w += __shfl_xor(v.w, m);
                }
                a4[bb][gg] = v;
            }

        // ---- lane (b=lane>>4, f=lane&15) stores its total: static select tree
        const int bsel = lane >> 4;
        const int gsel = (lane >> 2) & 3;
        const int csel = lane & 3;

        const float4 vg0 = sel4(gsel & 2, sel4(gsel & 1, a4[0][3], a4[0][2]),
                                          sel4(gsel & 1, a4[0][1], a4[0][0]));
        const float4 vg1 = sel4(gsel & 2, sel4(gsel & 1, a4[1][3], a4[1][2]),
                                          sel4(gsel & 1, a4[1][1], a4[1][0]));
        const float4 vg2 = sel4(gsel & 2, sel4(gsel & 1, a4[2][3], a4[2][2]),
                                          sel4(gsel & 1, a4[2][1], a4[2][0]));
        const float4 vg3 = sel4(gsel & 2, sel4(gsel & 1, a4[3][3], a4[3][2]),
                                          sel4(gsel & 1, a4[3][1], a4[3][0]));
        const float4 vb  = sel4(bsel & 2, sel4(bsel & 1, vg3, vg2),
                                          sel4(bsel & 1, vg1, vg0));
        const float v01 = (csel & 1) ? vb.y : vb.x;
        const float v23 = (csel & 1) ? vb.w : vb.z;
        const float val = (csel & 2) ? v23 : v01;

        outc[(size_t)(b0 + bsel) * (Ff * Cc) + (lane & 15) * Cc] = val;
    }
}

extern "C" void kernel_launch(void* const* d_in, const int* in_sizes, int n_in,
                              void* d_out, int out_size, void* d_ws, size_t ws_size,
                              hipStream_t stream) {
    const float* x = (const float*)d_in[0];
    const float* k = (const float*)d_in[1];
    float* out = (float*)d_out;
    const int grid = Cc;              // 256: one block per c, 1 per CU
    sle_kernel<<<grid, NTHREADS, 0, stream>>>(x, k, out);
}

// Round 4
// 391.502 us; speedup vs baseline: 1.2640x; 1.2640x over previous
//
#include <hip/hip_runtime.h>
#include <hip/hip_bf16.h>

// y[b,f,c] = sum_hw x[b,c,hw] * k[f,c,hw];  out[b, f*C + c]
// B=256, F=16, C=256, HW=1024, fp32.
//
// R4: no waves-per-eu hint. R7: K staged once in 64KB LDS, barrier-free loop.
// R8 (occupancy/XCD swizzle), R9 (RB=4): NEUTRAL.
// R10: contiguous 4KB-row bursts + per-si butterfly -> 240us REGRESSION
//   (serial load->compute->reduce phases, 8 waves/CU; VALUBusy 19%, 2.3TB/s).
//   Overhead recalibrated from R10's directly-measured kernel:
//   O = 494.9-240.8 ~= 254us  =>  R0/R8/R9 kernels were ~128-136us.
//   KEY COUNTER FACT (R10): WRITE_SIZE = 90 MB vs 4.2 MB ideal (21x) --
//   scattered per-c dword stores (16 blocks share each 64B out-line) are
//   unmerged partial-line RMWs; same store path in ALL prior kernels
//   => ~175 MB of RMW traffic.
// R11 (this round): R9 compute loop UNCHANGED; store block-contiguous
//   yT[c][b][f] to workspace (1 coalesced float4/thread), then a 64x64
//   LDS-tile transpose kernel writes out[b][f*C+c] (4MB+4MB, ~4us).
//   Fallback to direct stores if ws_size < 4MB.
//   Predict: dur 390 -> ~350-370. If neutral: write path exonerated,
//   remaining invariant = read-stream DRAM ceiling -> roofline next round.

constexpr int Bb = 256;
constexpr int Ff = 16;
constexpr int Cc = 256;
constexpr int HW = 1024;
constexpr int CHW = Cc * HW;

constexpr int BT = 128;            // b per block
constexpr int RB = 4;              // b per thread
constexpr int NTHREADS = (BT / RB) * 16;   // 512
constexpr int NJ = HW / 4 / 16;    // 16 j-iters (whole hw range)

__device__ __forceinline__ float dot4(float4 a, float4 b) {
    return a.x * b.x + a.y * b.y + a.z * b.z + a.w * b.w;
}
__device__ __forceinline__ float red16(float v) {
    v += __shfl_xor(v, 1);
    v += __shfl_xor(v, 2);
    v += __shfl_xor(v, 4);
    v += __shfl_xor(v, 8);
    return v;
}

template <bool TO_WS>
__global__ __launch_bounds__(NTHREADS)
void sle_kernel(const float* __restrict__ x, const float* __restrict__ k,
                float* __restrict__ dst) {   // TO_WS ? yT[c][b][f] : out[b][f*C+c]
    __shared__ float ldsK[Ff * HW];           // 64 KiB: whole K for this c

    const int t   = threadIdx.x;
    const int thw = t & 15;                   // hw split within 16-lane group
    const int tbg = t >> 4;                   // 0..31, b group

    // XCD-aware decode: same-c blocks share g%8; XCD owns 32-c chunk
    const int g     = blockIdx.x;
    const int c     = (g & 7) * 32 + ((g >> 3) & 31);
    const int btile = g >> 8;                 // 0..1
    const int b0    = btile * BT + tbg * RB;

    // ---- stage K[f][0..HW) for this c: 16384 floats, 8 float4/thread ----
    {
        const int fr = t >> 5, lane32 = t & 31;   // 32 threads per f-row
        const float4* src = (const float4*)(k + (size_t)fr * CHW + (size_t)c * HW);
        float4* dstk = (float4*)(ldsK + fr * HW);
#pragma unroll
        for (int q = 0; q < 8; ++q)
            dstk[lane32 + 32 * q] = src[lane32 + 32 * q];
    }
    __syncthreads();

    const float* xb = x + (size_t)c * HW;
    const int xo0 = (b0 + 0) * CHW;
    const int xo1 = (b0 + 1) * CHW;
    const int xo2 = (b0 + 2) * CHW;
    const int xo3 = (b0 + 3) * CHW;

    float4 a00={0,0,0,0}, a01={0,0,0,0}, a02={0,0,0,0}, a03={0,0,0,0};
    float4 a10={0,0,0,0}, a11={0,0,0,0}, a12={0,0,0,0}, a13={0,0,0,0};
    float4 a20={0,0,0,0}, a21={0,0,0,0}, a22={0,0,0,0}, a23={0,0,0,0};
    float4 a30={0,0,0,0}, a31={0,0,0,0}, a32={0,0,0,0}, a33={0,0,0,0};

    // ---- barrier-free main loop over the whole hw range (R9, unchanged) ----
#pragma unroll 2
    for (int j = 0; j < NJ; ++j) {
        const int off = 4 * (thw + 16 * j);
        const float4 xv0 = *(const float4*)(xb + xo0 + off);
        const float4 xv1 = *(const float4*)(xb + xo1 + off);
        const float4 xv2 = *(const float4*)(xb + xo2 + off);
        const float4 xv3 = *(const float4*)(xb + xo3 + off);

#define ACC_G(G, A0, A1, A2, A3) {                                      \
        const float* kp = ldsK + (4 * (G)) * HW + off;                  \
        const float4 k0 = *(const float4*)(kp);                         \
        const float4 k1 = *(const float4*)(kp + HW);                    \
        const float4 k2 = *(const float4*)(kp + 2 * HW);                \
        const float4 k3 = *(const float4*)(kp + 3 * HW);                \
        A0.x += dot4(xv0, k0); A0.y += dot4(xv0, k1);                   \
        A0.z += dot4(xv0, k2); A0.w += dot4(xv0, k3);                   \
        A1.x += dot4(xv1, k0); A1.y += dot4(xv1, k1);                   \
        A1.z += dot4(xv1, k2); A1.w += dot4(xv1, k3);                   \
        A2.x += dot4(xv2, k0); A2.y += dot4(xv2, k1);                   \
        A2.z += dot4(xv2, k2); A2.w += dot4(xv2, k3);                   \
        A3.x += dot4(xv3, k0); A3.y += dot4(xv3, k1);                   \
        A3.z += dot4(xv3, k2); A3.w += dot4(xv3, k3); }

        ACC_G(0, a00, a10, a20, a30)
        ACC_G(1, a01, a11, a21, a31)
        ACC_G(2, a02, a12, a22, a32)
        ACC_G(3, a03, a13, a23, a33)
#undef ACC_G
    }

    // reduce the 16 hw-split lanes; all lanes valid (butterfly)
#define RED4(A) { A.x = red16(A.x); A.y = red16(A.y); \
                  A.z = red16(A.z); A.w = red16(A.w); }
    RED4(a00) RED4(a01) RED4(a02) RED4(a03)
    RED4(a10) RED4(a11) RED4(a12) RED4(a13)
    RED4(a20) RED4(a21) RED4(a22) RED4(a23)
    RED4(a30) RED4(a31) RED4(a32) RED4(a33)
#undef RED4

    __syncthreads();                          // done reading ldsK as K-tile
    if (thw == 0) {
        float4* r0 = (float4*)(ldsK + (tbg * RB + 0) * Ff);
        float4* r1 = (float4*)(ldsK + (tbg * RB + 1) * Ff);
        float4* r2 = (float4*)(ldsK + (tbg * RB + 2) * Ff);
        float4* r3 = (float4*)(ldsK + (tbg * RB + 3) * Ff);
        r0[0] = a00; r0[1] = a01; r0[2] = a02; r0[3] = a03;
        r1[0] = a10; r1[1] = a11; r1[2] = a12; r1[3] = a13;
        r2[0] = a20; r2[1] = a21; r2[2] = a22; r2[3] = a23;
        r3[0] = a30; r3[1] = a31; r3[2] = a32; r3[3] = a33;
    }
    __syncthreads();
    // ldsK[0..2047] = results, idx = bl*16 + f  (bl local 0..127)

    if (TO_WS) {
        // block-contiguous coalesced store: yT[c][btile*128 + bl][f]
        float4 v = *(const float4*)(ldsK + 4 * t);
        *(float4*)(dst + (size_t)c * (Bb * Ff) + btile * (BT * Ff) + 4 * t) = v;
    } else {
        // fallback: direct scattered stores (legacy path)
#pragma unroll
        for (int i = 0; i < (BT * Ff) / NTHREADS; ++i) {   // 4
            const int idx = t + NTHREADS * i;
            const int bl  = idx >> 4;
            const int f   = idx & 15;
            dst[(size_t)(btile * BT + bl) * (Ff * Cc) + f * Cc + c] = ldsK[idx];
        }
    }
}

// out[r][c] = yT[c][r], with r = b*16+f (R = 4096), c = channel (C = 256).
constexpr int TS = 64;
__global__ __launch_bounds__(256)
void trans_kernel(const float* __restrict__ yT, float* __restrict__ out) {
    __shared__ float tl[TS][TS + 1];
    const int t  = threadIdx.x;
    const int bi = blockIdx.x & 63;           // r-tile: 4096/64
    const int bj = blockIdx.x >> 6;           // c-tile: 256/64 -> 0..3
    const int r0 = bi * TS, c0 = bj * TS;
    const int rr = t & 15, cl = t >> 4;

#pragma unroll
    for (int q = 0; q < 4; ++q) {             // load: rows of yT (coalesced)
        const int c_local = cl + 16 * q;
        const float4 v = *(const float4*)(yT + (size_t)(c0 + c_local) * 4096
                                              + r0 + 4 * rr);
        tl[c_local][4 * rr + 0] = v.x;
        tl[c_local][4 * rr + 1] = v.y;
        tl[c_local][4 * rr + 2] = v.z;
        tl[c_local][4 * rr + 3] = v.w;
    }
    __syncthreads();
#pragma unroll
    for (int q = 0; q < 4; ++q) {             // store: rows of out (coalesced)
        const int r_local = cl + 16 * q;
        float4 v;
        v.x = tl[4 * rr + 0][r_local];
        v.y = tl[4 * rr + 1][r_local];
        v.z = tl[4 * rr + 2][r_local];
        v.w = tl[4 * rr + 3][r_local];
        *(float4*)(out + (size_t)(r0 + r_local) * 256 + c0 + 4 * rr) = v;
    }
}

extern "C" void kernel_launch(void* const* d_in, const int* in_sizes, int n_in,
                              void* d_out, int out_size, void* d_ws, size_t ws_size,
                              hipStream_t stream) {
    const float* x = (const float*)d_in[0];
    const float* k = (const float*)d_in[1];
    float* out = (float*)d_out;
    const int grid = Cc * (Bb / BT);  // 512
    const size_t need = (size_t)Cc * Bb * Ff * sizeof(float);   // 4 MiB
    if (ws_size >= need && d_ws != nullptr) {
        float* yT = (float*)d_ws;
        sle_kernel<true><<<grid, NTHREADS, 0, stream>>>(x, k, yT);
        trans_kernel<<<256, 256, 0, stream>>>(yT, out);
    } else {
        sle_kernel<false><<<grid, NTHREADS, 0, stream>>>(x, k, out);
    }
}